// Round 9
// baseline (254.784 us; speedup 1.0000x reference)
//
#include <hip/hip_runtime.h>

#define B_  2
#define L_  2048
#define D_  2048
#define H_  16
#define DH_ 128
#define K_  2048

// 1/sqrt(128) * log2(e): scores computed in log2-units (exp via v_exp_f32 directly)
#define SCALEQ_ 0.12751734f

typedef __attribute__((ext_vector_type(8))) short bf16x8;
typedef __attribute__((ext_vector_type(4))) float f32x4;
typedef __attribute__((ext_vector_type(4))) float float4v;
typedef __attribute__((ext_vector_type(8))) unsigned short u16x8;
typedef __attribute__((ext_vector_type(4))) unsigned short u16x4;

__device__ __forceinline__ unsigned short f2bf(float f) {
  unsigned u = __builtin_bit_cast(unsigned, f);
  u += 0x7fffu + ((u >> 16) & 1u);
  return (unsigned short)(u >> 16);
}

__device__ __forceinline__ float exp2i(float x) {
  float r;
  asm("v_exp_f32 %0, %1" : "=v"(r) : "v"(x));
  return r;
}

typedef __attribute__((address_space(3))) unsigned int lds_uint;
typedef __attribute__((address_space(1))) const unsigned int glob_uint;
__device__ __forceinline__ void gld16(const void* g, void* l) {
  __builtin_amdgcn_global_load_lds((glob_uint*)g, (lds_uint*)l, 16, 0, 0);
}

#define BAR() do { asm volatile("" ::: "memory"); __builtin_amdgcn_s_barrier(); asm volatile("" ::: "memory"); } while (0)
#define VMCNT(n) asm volatile("s_waitcnt vmcnt(" #n ")" ::: "memory")

// ---------------- f32 -> bf16 prepass (weights + activations) ----------------
__global__ void cvt_all(const float* __restrict__ wq, const float* __restrict__ wk,
                        const float* __restrict__ wv, const float* __restrict__ wo,
                        const float* __restrict__ q, const float* __restrict__ k,
                        const float* __restrict__ v, unsigned short* __restrict__ ws,
                        int nacts) {
  const size_t DD = (size_t)D_ * D_;
  const size_t BLD = (size_t)B_ * L_ * D_;
  const int z = blockIdx.z;
  const float* src;
  unsigned short* dst;
  size_t nelem;
  if (z < 4) {
    src = (z == 0) ? wq : (z == 1) ? wk : (z == 2) ? wv : wo;
    dst = ws + (size_t)z * DD;
    nelem = DD;
  } else {
    if (z - 4 >= nacts) return;
    src = (z == 4) ? q : (z == 5) ? k : v;
    dst = ws + 4 * DD + (size_t)(z - 4) * BLD;
    nelem = BLD;
  }
  size_t i = ((size_t)blockIdx.x * 256 + threadIdx.x) * 8;
  if (i >= nelem) return;
  float4v x0 = *(const float4v*)(src + i);
  float4v x1 = *(const float4v*)(src + i + 4);
  u16x8 p;
  p[0]=f2bf(x0[0]); p[1]=f2bf(x0[1]); p[2]=f2bf(x0[2]); p[3]=f2bf(x0[3]);
  p[4]=f2bf(x1[0]); p[5]=f2bf(x1[1]); p[6]=f2bf(x1[2]); p[7]=f2bf(x1[3]);
  *(u16x8*)(dst + i) = p;
}

// ---------------- K/V proj GEMM: BM=256 BN=256 BK=64, 8 waves x (128x64), 2-buf ----------------
__global__ __launch_bounds__(512, 2) void gemm256(
    const unsigned short* __restrict__ a0, const unsigned short* __restrict__ a1,
    const unsigned short* __restrict__ w0, const unsigned short* __restrict__ w1,
    unsigned short* __restrict__ Kh, unsigned short* __restrict__ Vt) {
  __shared__ unsigned short smem[2 * 32768];  // 128 KB

  const int lin = blockIdx.x + 16 * (blockIdx.y + 8 * blockIdx.z);
  const int s = (lin & 7) * 32 + (lin >> 3);
  const int mt = s & 15;
  const int r_ = s >> 4;
  const int ntile = r_ & 7;
  const int z = r_ >> 3;          // 0 -> K op, 1 -> V op

  const unsigned short* A = z ? a1 : a0;
  const unsigned short* W = z ? w1 : w0;

  const int bm0 = mt * 256;
  const int bn0 = ntile * 256;

  const int tid = threadIdx.x;
  const int wid = tid >> 6, lane = tid & 63;
  const int wr = wid >> 2;
  const int wc = wid & 3;
  const int l15 = lane & 15, l4 = lane >> 4;

  const unsigned short* gsrc[8];
  int ldst[8];
#pragma unroll
  for (int i = 0; i < 4; ++i) {
    const int c = i * 512 + tid, r = c >> 3, s0 = c & 7;
    gsrc[i] = A + (size_t)(bm0 + r) * K_ + ((s0 ^ (r & 7)) << 3);
    ldst[i] = c * 8;
    gsrc[4 + i] = W + (size_t)(bn0 + r) * K_ + ((s0 ^ (r & 7)) << 3);
    ldst[4 + i] = 16384 + c * 8;
  }
#define STAGE(idx, p) do { gld16(gsrc[idx], &smem[(p) * 32768 + ldst[idx]]); gsrc[idx] += 64; } while (0)

  int offA[8][2], offB[4][2];
#pragma unroll
  for (int mf = 0; mf < 8; ++mf)
#pragma unroll
    for (int ks = 0; ks < 2; ++ks) {
      const int row = wr * 128 + mf * 16 + l15;
      const int ch = ks * 4 + l4;
      offA[mf][ks] = row * 64 + ((ch ^ (row & 7)) << 3);
    }
#pragma unroll
  for (int nf = 0; nf < 4; ++nf)
#pragma unroll
    for (int ks = 0; ks < 2; ++ks) {
      const int rowb = wc * 64 + nf * 16 + l15;
      const int ch = ks * 4 + l4;
      offB[nf][ks] = 16384 + rowb * 64 + ((ch ^ (rowb & 7)) << 3);
    }

  f32x4 acc[8][4];
#pragma unroll
  for (int m = 0; m < 8; ++m)
#pragma unroll
    for (int n = 0; n < 4; ++n) { f32x4 zz = {0.f, 0.f, 0.f, 0.f}; acc[m][n] = zz; }

  STAGE(0, 0); STAGE(1, 0); STAGE(2, 0); STAGE(3, 0);
  STAGE(4, 0); STAGE(5, 0); STAGE(6, 0); STAGE(7, 0);
  VMCNT(0);
  BAR();

  int p = 0;
  for (int t = 0; t < 32; ++t) {
    const int p2 = p ^ 1;
    if (t < 31) {
      STAGE(0, p2); STAGE(1, p2); STAGE(2, p2); STAGE(3, p2);
      STAGE(4, p2); STAGE(5, p2); STAGE(6, p2); STAGE(7, p2);
    }
    const unsigned short* bA = &smem[p * 32768];
    bf16x8 bfr[4][2];
#pragma unroll
    for (int nf = 0; nf < 4; ++nf)
#pragma unroll
      for (int ks = 0; ks < 2; ++ks)
        bfr[nf][ks] = *(const bf16x8*)&bA[offB[nf][ks]];
    __builtin_amdgcn_s_setprio(1);
#pragma unroll
    for (int mf = 0; mf < 8; ++mf) {
      bf16x8 a0f = *(const bf16x8*)&bA[offA[mf][0]];
      bf16x8 a1f = *(const bf16x8*)&bA[offA[mf][1]];
#pragma unroll
      for (int nf = 0; nf < 4; ++nf) {
        acc[mf][nf] = __builtin_amdgcn_mfma_f32_16x16x32_bf16(a0f, bfr[nf][0], acc[mf][nf], 0, 0, 0);
        acc[mf][nf] = __builtin_amdgcn_mfma_f32_16x16x32_bf16(a1f, bfr[nf][1], acc[mf][nf], 0, 0, 0);
      }
    }
    __builtin_amdgcn_s_setprio(0);
    VMCNT(0);
    BAR();
    p = p2;
  }
#undef STAGE

  if (z == 0) {
#pragma unroll
    for (int mf = 0; mf < 8; ++mf) {
      const int rr = bm0 + wr * 128 + mf * 16 + l4 * 4;
#pragma unroll
      for (int nf = 0; nf < 4; ++nf) {
        const int cc = bn0 + wc * 64 + nf * 16 + l15;
        const int h = cc >> 7, dh = cc & 127;
#pragma unroll
        for (int j = 0; j < 4; ++j) {
          const int r2 = rr + j;
          Kh[((size_t)((r2 >> 11) * H_ + h) * L_ + (r2 & 2047)) * DH_ + dh] = f2bf(acc[mf][nf][j]);
        }
      }
    }
  } else {
    unsigned short* T = smem;  // [256 n][144 m-pad]
    const int b = bm0 >> 11, lb = bm0 & 2047;
#pragma unroll 1
    for (int half = 0; half < 2; ++half) {
      if (half) __syncthreads();
      if (wr == half) {
#pragma unroll
        for (int mf = 0; mf < 8; ++mf) {
          const int rl = mf * 16 + l4 * 4;
#pragma unroll
          for (int nf = 0; nf < 4; ++nf) {
            const int cl = wc * 64 + nf * 16 + l15;
            u16x4 vv;
#pragma unroll
            for (int j = 0; j < 4; ++j) vv[j] = f2bf(acc[mf][nf][j]);
            *(u16x4*)&T[cl * 144 + rl] = vv;
          }
        }
      }
      __syncthreads();
#pragma unroll
      for (int it = 0; it < 8; ++it) {
        const int idx = it * 512 + tid;
        const int rT = idx >> 4, cT = idx & 15;
        u16x8 val = *(const u16x8*)&T[rT * 144 + cT * 8];
        const int n = bn0 + rT, h = n >> 7, dh = n & 127;
        *(u16x8*)&Vt[((size_t)(b * H_ + h) * DH_ + dh) * L_ + lb + half * 128 + cT * 8] = val;
      }
    }
  }
}

// ---------------- ring-3 GEMM: BM=128 BN=256 BK=64, 8 waves (2M x 4N) ----------------
// OUT=0: f32 C (final out-proj). OUT=1: bf16 head-major Qh, pre-scaled by SCALEQ_.
template <int OUT>
__global__ __launch_bounds__(512, 2) void gemm8p(
    const unsigned short* __restrict__ A, const unsigned short* __restrict__ W,
    void* __restrict__ outp) {
  __shared__ unsigned short smem[3 * 24576];  // 144 KB

  const int lin = blockIdx.x + 32 * blockIdx.y;
  const int s = (lin & 7) * 32 + (lin >> 3);
  const int mt = s & 31;
  const int ntile = s >> 5;

  const int bm0 = mt * 128;
  const int bn0 = ntile * 256;

  const int tid = threadIdx.x;
  const int wid = tid >> 6, lane = tid & 63;
  const int wr = wid >> 2, wc = wid & 3;
  const int l15 = lane & 15, l4 = lane >> 4;

  const unsigned short* gsrc[6];
  int ldst[6];
  {
#pragma unroll
    for (int i = 0; i < 2; ++i) {
      const int c = i * 512 + tid, r = c >> 3, s0 = c & 7;
      gsrc[i] = A + (size_t)(bm0 + r) * K_ + ((s0 ^ (r & 7)) << 3);
      ldst[i] = c * 8;
    }
#pragma unroll
    for (int u = 0; u < 2; ++u)
#pragma unroll
      for (int i = 0; i < 2; ++i) {
        const int c = i * 512 + tid, r = c >> 3, s0 = c & 7;
        gsrc[2 + u * 2 + i] = W + (size_t)(bn0 + u * 128 + r) * K_ + ((s0 ^ (r & 7)) << 3);
        ldst[2 + u * 2 + i] = 8192 + (u * 1024 + c) * 8;
      }
  }
#define STAGE(idx, p) do { gld16(gsrc[idx], &smem[(p) * 24576 + ldst[idx]]); gsrc[idx] += 64; } while (0)

  int offA[4][2], offB[4][2];
#pragma unroll
  for (int mf = 0; mf < 4; ++mf)
#pragma unroll
    for (int ks = 0; ks < 2; ++ks) {
      const int row = wr * 64 + mf * 16 + l15;
      const int ch = ks * 4 + l4;
      offA[mf][ks] = row * 64 + ((ch ^ (row & 7)) << 3);
    }
#pragma unroll
  for (int nf = 0; nf < 4; ++nf)
#pragma unroll
    for (int ks = 0; ks < 2; ++ks) {
      const int rowb = wc * 64 + nf * 16 + l15;
      const int ch = ks * 4 + l4;
      offB[nf][ks] = 8192 + rowb * 64 + ((ch ^ (rowb & 7)) << 3);
    }

  f32x4 acc[4][4];
#pragma unroll
  for (int m = 0; m < 4; ++m)
#pragma unroll
    for (int n = 0; n < 4; ++n) { f32x4 zz = {0.f, 0.f, 0.f, 0.f}; acc[m][n] = zz; }

  STAGE(0, 0); STAGE(1, 0); STAGE(2, 0); STAGE(3, 0); STAGE(4, 0); STAGE(5, 0);
  STAGE(0, 1); STAGE(1, 1); STAGE(2, 1); STAGE(3, 1); STAGE(4, 1); STAGE(5, 1);
  VMCNT(6);
  BAR();

  int p = 0;
  for (int t = 0; t < 32; ++t) {
    int p2 = p + 2; if (p2 >= 3) p2 -= 3;
    const unsigned short* bA = &smem[p * 24576];
    bf16x8 af[4][2], bfr[4][2];
#pragma unroll
    for (int mf = 0; mf < 4; ++mf)
#pragma unroll
      for (int ks = 0; ks < 2; ++ks)
        af[mf][ks] = *(const bf16x8*)&bA[offA[mf][ks]];
#pragma unroll
    for (int nf = 0; nf < 4; ++nf)
#pragma unroll
      for (int ks = 0; ks < 2; ++ks)
        bfr[nf][ks] = *(const bf16x8*)&bA[offB[nf][ks]];
    if (t < 30) { STAGE(0, p2); STAGE(1, p2); STAGE(2, p2); STAGE(3, p2); STAGE(4, p2); STAGE(5, p2); }
    __builtin_amdgcn_s_setprio(1);
#pragma unroll
    for (int mf = 0; mf < 4; ++mf)
#pragma unroll
      for (int nf = 0; nf < 4; ++nf)
#pragma unroll
        for (int ks = 0; ks < 2; ++ks)
          acc[mf][nf] = __builtin_amdgcn_mfma_f32_16x16x32_bf16(af[mf][ks], bfr[nf][ks], acc[mf][nf], 0, 0, 0);
    __builtin_amdgcn_s_setprio(0);
    if (t < 30) { VMCNT(6); } else { VMCNT(0); }
    BAR();
    p = (p == 2) ? 0 : p + 1;
  }
#undef STAGE

  if (OUT == 0) {
    float* OF = (float*)outp;
#pragma unroll
    for (int mf = 0; mf < 4; ++mf) {
      const int rr = bm0 + wr * 64 + mf * 16 + l4 * 4;
#pragma unroll
      for (int nf = 0; nf < 4; ++nf) {
        const int cc = bn0 + wc * 64 + nf * 16 + l15;
#pragma unroll
        for (int j = 0; j < 4; ++j) OF[(size_t)(rr + j) * D_ + cc] = acc[mf][nf][j];
      }
    }
  } else {
    unsigned short* O = (unsigned short*)outp;
#pragma unroll
    for (int mf = 0; mf < 4; ++mf) {
      const int rr = bm0 + wr * 64 + mf * 16 + l4 * 4;
#pragma unroll
      for (int nf = 0; nf < 4; ++nf) {
        const int cc = bn0 + wc * 64 + nf * 16 + l15;
        const int h = cc >> 7, dh = cc & 127;
#pragma unroll
        for (int j = 0; j < 4; ++j) {
          const int r2 = rr + j;
          O[((size_t)((r2 >> 11) * H_ + h) * L_ + (r2 & 2047)) * DH_ + dh] = f2bf(acc[mf][nf][j] * SCALEQ_);
        }
      }
    }
  }
}

// ---------------- fallback 128x128 proj GEMM (f32 A), only if ws too small ----------------
__global__ __launch_bounds__(256, 2) void proj_gemm_f32a(
    const float* __restrict__ q, const float* __restrict__ k, const float* __restrict__ v,
    const unsigned short* __restrict__ wqb, const unsigned short* __restrict__ wkb,
    const unsigned short* __restrict__ wvb,
    unsigned short* __restrict__ Qh, unsigned short* __restrict__ Kh,
    unsigned short* __restrict__ Vt) {
  __shared__ unsigned short smem[128 * 136];
  unsigned short* As = smem;
  unsigned short* Bs = smem + 128 * 64;

  const int z = blockIdx.z;
  const float* A = (z == 0) ? q : (z == 1) ? k : v;
  const unsigned short* W = (z == 0) ? wqb : (z == 1) ? wkb : wvb;

  const int tid = threadIdx.x;
  const int wave = tid >> 6, lane = tid & 63;
  const int wr = wave >> 1, wc = wave & 1;
  const int bm0 = blockIdx.x * 128;
  const int bn0 = blockIdx.y * 128;
  const int l15 = lane & 15, l4 = lane >> 4;

  f32x4 acc[4][4];
#pragma unroll
  for (int m = 0; m < 4; m++)
#pragma unroll
    for (int n = 0; n < 4; n++) { f32x4 zz = {0.f, 0.f, 0.f, 0.f}; acc[m][n] = zz; }

  for (int k0 = 0; k0 < K_; k0 += 64) {
#pragma unroll
    for (int it = 0; it < 4; ++it) {
      const int base = it * 256 + wave * 64;
      const int ch = base + lane;
      const int r = ch >> 3, c = ch & 7;
      gld16(W + (size_t)(bn0 + r) * K_ + (k0 + c * 8), Bs + base * 8);
    }
#pragma unroll
    for (int it = 0; it < 4; ++it) {
      const int ch = it * 256 + tid;
      const int r = ch >> 3, c = ch & 7;
      const float* g = A + (size_t)(bm0 + r) * K_ + (k0 + c * 8);
      float4v x0 = *(const float4v*)g;
      float4v x1 = *(const float4v*)(g + 4);
      u16x8 pp;
      pp[0]=f2bf(x0[0]); pp[1]=f2bf(x0[1]); pp[2]=f2bf(x0[2]); pp[3]=f2bf(x0[3]);
      pp[4]=f2bf(x1[0]); pp[5]=f2bf(x1[1]); pp[6]=f2bf(x1[2]); pp[7]=f2bf(x1[3]);
      *(u16x8*)&As[ch * 8] = pp;
    }
    __syncthreads();
#pragma unroll
    for (int ks = 0; ks < 2; ++ks) {
      const int kc = ks * 32 + l4 * 8;
      bf16x8 af[4], bfr[4];
#pragma unroll
      for (int m = 0; m < 4; m++) af[m] = *(const bf16x8*)&As[(wr * 64 + m * 16 + l15) * 64 + kc];
#pragma unroll
      for (int n = 0; n < 4; n++) bfr[n] = *(const bf16x8*)&Bs[(wc * 64 + n * 16 + l15) * 64 + kc];
#pragma unroll
      for (int m = 0; m < 4; m++)
#pragma unroll
        for (int n = 0; n < 4; n++)
          acc[m][n] = __builtin_amdgcn_mfma_f32_16x16x32_bf16(af[m], bfr[n], acc[m][n], 0, 0, 0);
    }
    __syncthreads();
  }

  if (z < 2) {
    unsigned short* O = (z == 0) ? Qh : Kh;
    const float qsc = (z == 0) ? SCALEQ_ : 1.f;
#pragma unroll
    for (int m = 0; m < 4; m++) {
      const int rr = bm0 + wr * 64 + m * 16 + l4 * 4;
#pragma unroll
      for (int n = 0; n < 4; n++) {
        const int cc = bn0 + wc * 64 + n * 16 + l15;
        const int h = cc >> 7, dh = cc & 127;
#pragma unroll
        for (int j = 0; j < 4; j++) {
          const int r2 = rr + j;
          O[((size_t)((r2 >> 11) * H_ + h) * L_ + (r2 & 2047)) * DH_ + dh] = f2bf(acc[m][n][j] * qsc);
        }
      }
    }
  } else {
    __syncthreads();
    unsigned short* T = smem;  // [128][136]
#pragma unroll
    for (int m = 0; m < 4; m++)
#pragma unroll
      for (int n = 0; n < 4; n++) {
        const int cl = wc * 64 + n * 16 + l15;
        const int rl = wr * 64 + m * 16 + l4 * 4;
#pragma unroll
        for (int j = 0; j < 4; j++) T[cl * 136 + rl + j] = f2bf(acc[m][n][j]);
      }
    __syncthreads();
    const int b = bm0 >> 11, lbase = bm0 & 2047;
    const int hb = bn0 >> 7;
#pragma unroll
    for (int it = 0; it < 8; ++it) {
      const int idx = it * 256 + tid;
      const int dhl = idx >> 4, c = idx & 15;
      u16x8 val = *(const u16x8*)&T[dhl * 136 + c * 8];
      *(u16x8*)&Vt[((size_t)(b * H_ + hb) * DH_ + dhl) * L_ + lbase + c * 8] = val;
    }
  }
}

// ---------------- causal flash attention: QBLK=128, KVBLK=64, tri-ring + counted vmcnt ----------------
// Swapped QK (lane holds q-row l15), in-reg softmax. K/V tri-buffered: stage(t+2) into
// buf[(t+2)%3] = buffer of dead tile t-1 (reads fenced by BAR(t-1)); ONE barrier + ONE
// counted VMCNT(8) per tile, never draining in steady state (T3/T4). Ps stride 72 shorts
// (144 B == 16 mod 128 -> bank stride 4 -> 2-way = free; 16-B aligned for b128 reads).
__global__ __launch_bounds__(512, 2) void attn_kernel(
    const unsigned short* __restrict__ Qh, const unsigned short* __restrict__ Kh,
    const unsigned short* __restrict__ Vt, unsigned short* __restrict__ ctx) {
  __shared__ unsigned short Ks[3][64 * 128];  // 48 KB, [key][dh] chunk-swizzled
  __shared__ unsigned short Vs[3][128 * 64];  // 48 KB, [dh][key] chunk-swizzled
  __shared__ unsigned short Ps[8][16 * 72];   // 18 KB, per-wave P [qrow16][key64+pad]

  const int lin0 = blockIdx.x + 8 * blockIdx.y;
  const int w = (lin0 & 7) * 32 + (lin0 >> 3);  // 8 same-bh blocks per XCD (KV L2 locality)
  const int pair = w & 7, bh = w >> 3;

  const size_t hoff = (size_t)bh * L_ * DH_;
  const unsigned short* Qp = Qh + hoff;
  const unsigned short* Kp = Kh + hoff;
  const unsigned short* Vp = Vt + hoff;

  const int tid = threadIdx.x, wave = tid >> 6, lane = tid & 63;
  const int l15 = lane & 15, l4 = lane >> 4;
  const int b = bh >> 4, h = bh & 15;

  // stage K tile (64 keys x 128 dh) + V tile (128 dh x 64 keys): 4 gld16/thread each... 2 each.
#define STAGEKV(kt, buf) do { \
  _Pragma("unroll") \
  for (int it = 0; it < 2; ++it) { \
    const int ch = it * 512 + tid; \
    const int r = ch >> 4, s2 = ch & 15; \
    gld16(Kp + (size_t)((kt) * 64 + r) * DH_ + ((s2 ^ (r & 7)) * 8), (unsigned short*)&Ks[buf][0] + ch * 8); \
  } \
  _Pragma("unroll") \
  for (int it = 0; it < 2; ++it) { \
    const int ch = it * 512 + tid; \
    const int r = ch >> 3, s2 = ch & 7; \
    gld16(Vp + (size_t)r * L_ + (kt) * 64 + ((s2 ^ (r & 7)) * 8), (unsigned short*)&Vs[buf][0] + ch * 8); \
  } } while (0)

#pragma unroll 1
  for (int pp = 0; pp < 2; ++pp) {
    const int qt = pp ? (15 - pair) : pair;   // q-tile of 128 rows
    const int nt = 2 * qt + 2;                // KV-64 tiles

    bf16x8 qf[4];
    {
      const int qrow = qt * 128 + wave * 16 + l15;
#pragma unroll
      for (int s = 0; s < 4; s++)
        qf[s] = *(const bf16x8*)&Qp[(size_t)qrow * DH_ + s * 32 + l4 * 8];
    }

    f32x4 o[8];
#pragma unroll
    for (int df = 0; df < 8; df++) { f32x4 zz = {0.f, 0.f, 0.f, 0.f}; o[df] = zz; }
    float m_r = -1e30f;
    float l_r = 0.f;

    // prologue: stage tiles 0,1; wait tile 0 (8 of tile 1 in flight)
    STAGEKV(0, 0);
    STAGEKV(1, 1);
    VMCNT(8);
    BAR();

    const int qg = qt * 128 + wave * 16 + l15;  // this lane's q-row (global)
    int cur = 0;
#pragma unroll 1
    for (int kt = 0; kt < nt; ++kt) {
      // S^T: sa[f][j] = S[qrow=l15][key = kt*64 + f*16 + l4*4 + j]
      f32x4 sa[4];
#pragma unroll
      for (int f = 0; f < 4; f++) { f32x4 zz = {0.f, 0.f, 0.f, 0.f}; sa[f] = zz; }
      __builtin_amdgcn_s_setprio(1);
#pragma unroll
      for (int ks = 0; ks < 4; ++ks) {
        const int c = ks * 4 + l4;
#pragma unroll
        for (int f = 0; f < 4; ++f) {
          const int n = f * 16 + l15;
          bf16x8 kf = *(const bf16x8*)&Ks[cur][n * 128 + ((c ^ (n & 7)) * 8)];
          sa[f] = __builtin_amdgcn_mfma_f32_16x16x32_bf16(kf, qf[ks], sa[f], 0, 0, 0);
        }
      }
      __builtin_amdgcn_s_setprio(0);

      if (kt >= nt - 2) {  // diagonal 128-block spans the last two 64-key tiles
#pragma unroll
        for (int f = 0; f < 4; f++) {
          const int kg = kt * 64 + f * 16 + l4 * 4;
#pragma unroll
          for (int j = 0; j < 4; j++)
            if (kg + j > qg) sa[f][j] = -1e30f;
        }
      }

      // in-reg row softmax (row l15, replicated across 4 l4-lanes)
      float mx = -1e30f;
#pragma unroll
      for (int f = 0; f < 4; f++)
#pragma unroll
        for (int j = 0; j < 4; j++) mx = fmaxf(mx, sa[f][j]);
      mx = fmaxf(mx, __shfl_xor(mx, 16));
      mx = fmaxf(mx, __shfl_xor(mx, 32));
      const float mnew = fmaxf(m_r, mx);
      const float alpha = exp2i(m_r - mnew);
      float rs = 0.f;
#pragma unroll
      for (int f = 0; f < 4; f++) {
        u16x4 pk4;
#pragma unroll
        for (int j = 0; j < 4; j++) {
          float pv = exp2i(sa[f][j] - mnew);
          rs += pv;
          pk4[j] = f2bf(pv);
        }
        *(u16x4*)&Ps[wave][l15 * 72 + f * 16 + l4 * 4] = pk4;
      }
      rs += __shfl_xor(rs, 16);
      rs += __shfl_xor(rs, 32);
      l_r = l_r * alpha + rs;
      m_r = mnew;
#pragma unroll
      for (int j = 0; j < 4; j++) {
        const float aj = __shfl(alpha, l4 * 4 + j);
#pragma unroll
        for (int df = 0; df < 8; df++) o[df][j] *= aj;
      }

      // O += P V  (P from wave-private Ps; V from Vs[cur], landed with K at tile entry)
      __builtin_amdgcn_s_setprio(1);
#pragma unroll
      for (int ksl = 0; ksl < 2; ++ksl) {
        const int pc = ksl * 4 + l4;
        bf16x8 pf = *(const bf16x8*)&Ps[wave][l15 * 72 + ksl * 32 + l4 * 8];
#pragma unroll
        for (int df = 0; df < 8; ++df) {
          const int vr = df * 16 + l15;
          bf16x8 vf = *(const bf16x8*)&Vs[cur][vr * 64 + ((pc ^ (vr & 7)) * 8)];
          o[df] = __builtin_amdgcn_mfma_f32_16x16x32_bf16(pf, vf, o[df], 0, 0, 0);
        }
      }
      __builtin_amdgcn_s_setprio(0);

      // tile boundary: BAR fences this tile's reads, then stage t+2 into dead buffer,
      // counted wait for t+1 (8 in flight from t+2 in steady state)
      BAR();
      if (kt + 2 < nt) {
        int b2 = cur + 2; if (b2 >= 3) b2 -= 3;
        STAGEKV(kt + 2, b2);
        VMCNT(8);
      } else {
        VMCNT(0);
      }
      cur = (cur == 2) ? 0 : cur + 1;
    }
    BAR();  // all waves done with this q-tile's buffers before pp=1 restages

#pragma unroll
    for (int j = 0; j < 4; j++) {
      const float inv = 1.0f / __shfl(l_r, l4 * 4 + j);
      const int lq = qt * 128 + wave * 16 + l4 * 4 + j;
      const size_t rowb = ((size_t)(b * L_ + lq)) * D_ + h * DH_;
#pragma unroll
      for (int df = 0; df < 8; ++df)
        ctx[rowb + df * 16 + l15] = f2bf(o[df][j] * inv);
    }
  }
#undef STAGEKV
}

extern "C" void kernel_launch(void* const* d_in, const int* in_sizes, int n_in,
                              void* d_out, int out_size, void* d_ws, size_t ws_size,
                              hipStream_t stream) {
  const float* q  = (const float*)d_in[0];
  const float* k  = (const float*)d_in[1];
  const float* v  = (const float*)d_in[2];
  // d_in[3] = attn_mask: fixed causal triu(k=1); implemented analytically in-kernel
  const float* wq = (const float*)d_in[4];
  const float* wk = (const float*)d_in[5];
  const float* wv = (const float*)d_in[6];
  const float* wo = (const float*)d_in[7];

  const size_t DD = (size_t)D_ * D_;
  const size_t BLD = (size_t)B_ * L_ * D_;
  unsigned short* ws  = (unsigned short*)d_ws;
  unsigned short* wqb = ws;
  unsigned short* wkb = wqb + DD;
  unsigned short* wvb = wkb + DD;
  unsigned short* wob = wvb + DD;

  const size_t need_full = (4 * DD + 7 * BLD) * 2;  // ~151 MB

  if (ws_size >= need_full) {
    unsigned short* qb  = wob + DD;
    unsigned short* kb  = qb + BLD;
    unsigned short* vb  = kb + BLD;
    unsigned short* QhP = vb + BLD;
    unsigned short* KhP = QhP + BLD;
    unsigned short* VtP = KhP + BLD;
    unsigned short* ctx = VtP + BLD;

    cvt_all<<<dim3(4096, 1, 7), 256, 0, stream>>>(wq, wk, wv, wo, q, k, v, ws, 3);
    gemm256<<<dim3(16, 8, 2), 512, 0, stream>>>(kb, vb, wkb, wvb, KhP, VtP);
    gemm8p<1><<<dim3(32, 8), 512, 0, stream>>>(qb, wqb, QhP);
    attn_kernel<<<dim3(8, 32), 512, 0, stream>>>(QhP, KhP, VtP, ctx);
    gemm8p<0><<<dim3(32, 8), 512, 0, stream>>>(ctx, wob, d_out);
  } else {
    unsigned short* QhP = wob + DD;
    unsigned short* KhP = QhP + BLD;
    unsigned short* VtP = KhP + BLD;
    unsigned short* ctx = VtP + BLD;

    cvt_all<<<dim3(4096, 1, 4), 256, 0, stream>>>(wq, wk, wv, wo, q, k, v, ws, 0);
    proj_gemm_f32a<<<dim3(32, 16, 3), 256, 0, stream>>>(q, k, v, wqb, wkb, wvb, QhP, KhP, VtP);
    attn_kernel<<<dim3(8, 32), 512, 0, stream>>>(QhP, KhP, VtP, ctx);
    gemm8p<0><<<dim3(32, 8), 512, 0, stream>>>(ctx, wob, d_out);
  }
}

// Round 10
// 245.571 us; speedup vs baseline: 1.0375x; 1.0375x over previous
//
#include <hip/hip_runtime.h>

#define B_  2
#define L_  2048
#define D_  2048
#define H_  16
#define DH_ 128
#define K_  2048

// 1/sqrt(128) * log2(e): scores computed in log2-units (exp via v_exp_f32 directly)
#define SCALEQ_ 0.12751734f

typedef __attribute__((ext_vector_type(8))) short bf16x8;
typedef __attribute__((ext_vector_type(4))) float f32x4;
typedef __attribute__((ext_vector_type(4))) float float4v;
typedef __attribute__((ext_vector_type(8))) unsigned short u16x8;
typedef __attribute__((ext_vector_type(4))) unsigned short u16x4;

__device__ __forceinline__ unsigned short f2bf(float f) {
  unsigned u = __builtin_bit_cast(unsigned, f);
  u += 0x7fffu + ((u >> 16) & 1u);
  return (unsigned short)(u >> 16);
}

__device__ __forceinline__ float exp2i(float x) {
  float r;
  asm("v_exp_f32 %0, %1" : "=v"(r) : "v"(x));
  return r;
}

typedef __attribute__((address_space(3))) unsigned int lds_uint;
typedef __attribute__((address_space(1))) const unsigned int glob_uint;
__device__ __forceinline__ void gld16(const void* g, void* l) {
  __builtin_amdgcn_global_load_lds((glob_uint*)g, (lds_uint*)l, 16, 0, 0);
}

#define BAR() do { asm volatile("" ::: "memory"); __builtin_amdgcn_s_barrier(); asm volatile("" ::: "memory"); } while (0)
#define VMCNT(n) asm volatile("s_waitcnt vmcnt(" #n ")" ::: "memory")

// ---------------- f32 -> bf16 prepass (weights + activations) ----------------
__global__ void cvt_all(const float* __restrict__ wq, const float* __restrict__ wk,
                        const float* __restrict__ wv, const float* __restrict__ wo,
                        const float* __restrict__ q, const float* __restrict__ k,
                        const float* __restrict__ v, unsigned short* __restrict__ ws,
                        int nacts) {
  const size_t DD = (size_t)D_ * D_;
  const size_t BLD = (size_t)B_ * L_ * D_;
  const int z = blockIdx.z;
  const float* src;
  unsigned short* dst;
  size_t nelem;
  if (z < 4) {
    src = (z == 0) ? wq : (z == 1) ? wk : (z == 2) ? wv : wo;
    dst = ws + (size_t)z * DD;
    nelem = DD;
  } else {
    if (z - 4 >= nacts) return;
    src = (z == 4) ? q : (z == 5) ? k : v;
    dst = ws + 4 * DD + (size_t)(z - 4) * BLD;
    nelem = BLD;
  }
  size_t i = ((size_t)blockIdx.x * 256 + threadIdx.x) * 8;
  if (i >= nelem) return;
  float4v x0 = *(const float4v*)(src + i);
  float4v x1 = *(const float4v*)(src + i + 4);
  u16x8 p;
  p[0]=f2bf(x0[0]); p[1]=f2bf(x0[1]); p[2]=f2bf(x0[2]); p[3]=f2bf(x0[3]);
  p[4]=f2bf(x1[0]); p[5]=f2bf(x1[1]); p[6]=f2bf(x1[2]); p[7]=f2bf(x1[3]);
  *(u16x8*)(dst + i) = p;
}

// ---------------- K/V proj GEMM: BM=256 BN=256 BK=64, 8 waves x (128x64), 2-buf ----------------
__global__ __launch_bounds__(512, 2) void gemm256(
    const unsigned short* __restrict__ a0, const unsigned short* __restrict__ a1,
    const unsigned short* __restrict__ w0, const unsigned short* __restrict__ w1,
    unsigned short* __restrict__ Kh, unsigned short* __restrict__ Vt) {
  __shared__ unsigned short smem[2 * 32768];  // 128 KB

  const int lin = blockIdx.x + 16 * (blockIdx.y + 8 * blockIdx.z);
  const int s = (lin & 7) * 32 + (lin >> 3);
  const int mt = s & 15;
  const int r_ = s >> 4;
  const int ntile = r_ & 7;
  const int z = r_ >> 3;          // 0 -> K op, 1 -> V op

  const unsigned short* A = z ? a1 : a0;
  const unsigned short* W = z ? w1 : w0;

  const int bm0 = mt * 256;
  const int bn0 = ntile * 256;

  const int tid = threadIdx.x;
  const int wid = tid >> 6, lane = tid & 63;
  const int wr = wid >> 2;
  const int wc = wid & 3;
  const int l15 = lane & 15, l4 = lane >> 4;

  const unsigned short* gsrc[8];
  int ldst[8];
#pragma unroll
  for (int i = 0; i < 4; ++i) {
    const int c = i * 512 + tid, r = c >> 3, s0 = c & 7;
    gsrc[i] = A + (size_t)(bm0 + r) * K_ + ((s0 ^ (r & 7)) << 3);
    ldst[i] = c * 8;
    gsrc[4 + i] = W + (size_t)(bn0 + r) * K_ + ((s0 ^ (r & 7)) << 3);
    ldst[4 + i] = 16384 + c * 8;
  }
#define STAGE(idx, p) do { gld16(gsrc[idx], &smem[(p) * 32768 + ldst[idx]]); gsrc[idx] += 64; } while (0)

  int offA[8][2], offB[4][2];
#pragma unroll
  for (int mf = 0; mf < 8; ++mf)
#pragma unroll
    for (int ks = 0; ks < 2; ++ks) {
      const int row = wr * 128 + mf * 16 + l15;
      const int ch = ks * 4 + l4;
      offA[mf][ks] = row * 64 + ((ch ^ (row & 7)) << 3);
    }
#pragma unroll
  for (int nf = 0; nf < 4; ++nf)
#pragma unroll
    for (int ks = 0; ks < 2; ++ks) {
      const int rowb = wc * 64 + nf * 16 + l15;
      const int ch = ks * 4 + l4;
      offB[nf][ks] = 16384 + rowb * 64 + ((ch ^ (rowb & 7)) << 3);
    }

  f32x4 acc[8][4];
#pragma unroll
  for (int m = 0; m < 8; ++m)
#pragma unroll
    for (int n = 0; n < 4; ++n) { f32x4 zz = {0.f, 0.f, 0.f, 0.f}; acc[m][n] = zz; }

  STAGE(0, 0); STAGE(1, 0); STAGE(2, 0); STAGE(3, 0);
  STAGE(4, 0); STAGE(5, 0); STAGE(6, 0); STAGE(7, 0);
  VMCNT(0);
  BAR();

  int p = 0;
  for (int t = 0; t < 32; ++t) {
    const int p2 = p ^ 1;
    if (t < 31) {
      STAGE(0, p2); STAGE(1, p2); STAGE(2, p2); STAGE(3, p2);
      STAGE(4, p2); STAGE(5, p2); STAGE(6, p2); STAGE(7, p2);
    }
    const unsigned short* bA = &smem[p * 32768];
    bf16x8 bfr[4][2];
#pragma unroll
    for (int nf = 0; nf < 4; ++nf)
#pragma unroll
      for (int ks = 0; ks < 2; ++ks)
        bfr[nf][ks] = *(const bf16x8*)&bA[offB[nf][ks]];
    __builtin_amdgcn_s_setprio(1);
#pragma unroll
    for (int mf = 0; mf < 8; ++mf) {
      bf16x8 a0f = *(const bf16x8*)&bA[offA[mf][0]];
      bf16x8 a1f = *(const bf16x8*)&bA[offA[mf][1]];
#pragma unroll
      for (int nf = 0; nf < 4; ++nf) {
        acc[mf][nf] = __builtin_amdgcn_mfma_f32_16x16x32_bf16(a0f, bfr[nf][0], acc[mf][nf], 0, 0, 0);
        acc[mf][nf] = __builtin_amdgcn_mfma_f32_16x16x32_bf16(a1f, bfr[nf][1], acc[mf][nf], 0, 0, 0);
      }
    }
    __builtin_amdgcn_s_setprio(0);
    VMCNT(0);
    BAR();
    p = p2;
  }
#undef STAGE

  if (z == 0) {
#pragma unroll
    for (int mf = 0; mf < 8; ++mf) {
      const int rr = bm0 + wr * 128 + mf * 16 + l4 * 4;
#pragma unroll
      for (int nf = 0; nf < 4; ++nf) {
        const int cc = bn0 + wc * 64 + nf * 16 + l15;
        const int h = cc >> 7, dh = cc & 127;
#pragma unroll
        for (int j = 0; j < 4; ++j) {
          const int r2 = rr + j;
          Kh[((size_t)((r2 >> 11) * H_ + h) * L_ + (r2 & 2047)) * DH_ + dh] = f2bf(acc[mf][nf][j]);
        }
      }
    }
  } else {
    unsigned short* T = smem;  // [256 n][144 m-pad]
    const int b = bm0 >> 11, lb = bm0 & 2047;
#pragma unroll 1
    for (int half = 0; half < 2; ++half) {
      if (half) __syncthreads();
      if (wr == half) {
#pragma unroll
        for (int mf = 0; mf < 8; ++mf) {
          const int rl = mf * 16 + l4 * 4;
#pragma unroll
          for (int nf = 0; nf < 4; ++nf) {
            const int cl = wc * 64 + nf * 16 + l15;
            u16x4 vv;
#pragma unroll
            for (int j = 0; j < 4; ++j) vv[j] = f2bf(acc[mf][nf][j]);
            *(u16x4*)&T[cl * 144 + rl] = vv;
          }
        }
      }
      __syncthreads();
#pragma unroll
      for (int it = 0; it < 8; ++it) {
        const int idx = it * 512 + tid;
        const int rT = idx >> 4, cT = idx & 15;
        u16x8 val = *(const u16x8*)&T[rT * 144 + cT * 8];
        const int n = bn0 + rT, h = n >> 7, dh = n & 127;
        *(u16x8*)&Vt[((size_t)(b * H_ + h) * DH_ + dh) * L_ + lb + half * 128 + cT * 8] = val;
      }
    }
  }
}

// ---------------- ring-3 GEMM: BM=128 BN=256 BK=64, 8 waves (2M x 4N) ----------------
// OUT=0: f32 C (final out-proj). OUT=1: bf16 head-major Qh, pre-scaled by SCALEQ_.
template <int OUT>
__global__ __launch_bounds__(512, 2) void gemm8p(
    const unsigned short* __restrict__ A, const unsigned short* __restrict__ W,
    void* __restrict__ outp) {
  __shared__ unsigned short smem[3 * 24576];  // 144 KB

  const int lin = blockIdx.x + 32 * blockIdx.y;
  const int s = (lin & 7) * 32 + (lin >> 3);
  const int mt = s & 31;
  const int ntile = s >> 5;

  const int bm0 = mt * 128;
  const int bn0 = ntile * 256;

  const int tid = threadIdx.x;
  const int wid = tid >> 6, lane = tid & 63;
  const int wr = wid >> 2, wc = wid & 3;
  const int l15 = lane & 15, l4 = lane >> 4;

  const unsigned short* gsrc[6];
  int ldst[6];
  {
#pragma unroll
    for (int i = 0; i < 2; ++i) {
      const int c = i * 512 + tid, r = c >> 3, s0 = c & 7;
      gsrc[i] = A + (size_t)(bm0 + r) * K_ + ((s0 ^ (r & 7)) << 3);
      ldst[i] = c * 8;
    }
#pragma unroll
    for (int u = 0; u < 2; ++u)
#pragma unroll
      for (int i = 0; i < 2; ++i) {
        const int c = i * 512 + tid, r = c >> 3, s0 = c & 7;
        gsrc[2 + u * 2 + i] = W + (size_t)(bn0 + u * 128 + r) * K_ + ((s0 ^ (r & 7)) << 3);
        ldst[2 + u * 2 + i] = 8192 + (u * 1024 + c) * 8;
      }
  }
#define STAGE(idx, p) do { gld16(gsrc[idx], &smem[(p) * 24576 + ldst[idx]]); gsrc[idx] += 64; } while (0)

  int offA[4][2], offB[4][2];
#pragma unroll
  for (int mf = 0; mf < 4; ++mf)
#pragma unroll
    for (int ks = 0; ks < 2; ++ks) {
      const int row = wr * 64 + mf * 16 + l15;
      const int ch = ks * 4 + l4;
      offA[mf][ks] = row * 64 + ((ch ^ (row & 7)) << 3);
    }
#pragma unroll
  for (int nf = 0; nf < 4; ++nf)
#pragma unroll
    for (int ks = 0; ks < 2; ++ks) {
      const int rowb = wc * 64 + nf * 16 + l15;
      const int ch = ks * 4 + l4;
      offB[nf][ks] = 8192 + rowb * 64 + ((ch ^ (rowb & 7)) << 3);
    }

  f32x4 acc[4][4];
#pragma unroll
  for (int m = 0; m < 4; ++m)
#pragma unroll
    for (int n = 0; n < 4; ++n) { f32x4 zz = {0.f, 0.f, 0.f, 0.f}; acc[m][n] = zz; }

  STAGE(0, 0); STAGE(1, 0); STAGE(2, 0); STAGE(3, 0); STAGE(4, 0); STAGE(5, 0);
  STAGE(0, 1); STAGE(1, 1); STAGE(2, 1); STAGE(3, 1); STAGE(4, 1); STAGE(5, 1);
  VMCNT(6);
  BAR();

  int p = 0;
  for (int t = 0; t < 32; ++t) {
    int p2 = p + 2; if (p2 >= 3) p2 -= 3;
    const unsigned short* bA = &smem[p * 24576];
    bf16x8 af[4][2], bfr[4][2];
#pragma unroll
    for (int mf = 0; mf < 4; ++mf)
#pragma unroll
      for (int ks = 0; ks < 2; ++ks)
        af[mf][ks] = *(const bf16x8*)&bA[offA[mf][ks]];
#pragma unroll
    for (int nf = 0; nf < 4; ++nf)
#pragma unroll
      for (int ks = 0; ks < 2; ++ks)
        bfr[nf][ks] = *(const bf16x8*)&bA[offB[nf][ks]];
    if (t < 30) { STAGE(0, p2); STAGE(1, p2); STAGE(2, p2); STAGE(3, p2); STAGE(4, p2); STAGE(5, p2); }
    __builtin_amdgcn_s_setprio(1);
#pragma unroll
    for (int mf = 0; mf < 4; ++mf)
#pragma unroll
      for (int nf = 0; nf < 4; ++nf)
#pragma unroll
        for (int ks = 0; ks < 2; ++ks)
          acc[mf][nf] = __builtin_amdgcn_mfma_f32_16x16x32_bf16(af[mf][ks], bfr[nf][ks], acc[mf][nf], 0, 0, 0);
    __builtin_amdgcn_s_setprio(0);
    if (t < 30) { VMCNT(6); } else { VMCNT(0); }
    BAR();
    p = (p == 2) ? 0 : p + 1;
  }
#undef STAGE

  if (OUT == 0) {
    float* OF = (float*)outp;
#pragma unroll
    for (int mf = 0; mf < 4; ++mf) {
      const int rr = bm0 + wr * 64 + mf * 16 + l4 * 4;
#pragma unroll
      for (int nf = 0; nf < 4; ++nf) {
        const int cc = bn0 + wc * 64 + nf * 16 + l15;
#pragma unroll
        for (int j = 0; j < 4; ++j) OF[(size_t)(rr + j) * D_ + cc] = acc[mf][nf][j];
      }
    }
  } else {
    unsigned short* O = (unsigned short*)outp;
#pragma unroll
    for (int mf = 0; mf < 4; ++mf) {
      const int rr = bm0 + wr * 64 + mf * 16 + l4 * 4;
#pragma unroll
      for (int nf = 0; nf < 4; ++nf) {
        const int cc = bn0 + wc * 64 + nf * 16 + l15;
        const int h = cc >> 7, dh = cc & 127;
#pragma unroll
        for (int j = 0; j < 4; ++j) {
          const int r2 = rr + j;
          O[((size_t)((r2 >> 11) * H_ + h) * L_ + (r2 & 2047)) * DH_ + dh] = f2bf(acc[mf][nf][j] * SCALEQ_);
        }
      }
    }
  }
}

// ---------------- fallback 128x128 proj GEMM (f32 A), only if ws too small ----------------
__global__ __launch_bounds__(256, 2) void proj_gemm_f32a(
    const float* __restrict__ q, const float* __restrict__ k, const float* __restrict__ v,
    const unsigned short* __restrict__ wqb, const unsigned short* __restrict__ wkb,
    const unsigned short* __restrict__ wvb,
    unsigned short* __restrict__ Qh, unsigned short* __restrict__ Kh,
    unsigned short* __restrict__ Vt) {
  __shared__ unsigned short smem[128 * 136];
  unsigned short* As = smem;
  unsigned short* Bs = smem + 128 * 64;

  const int z = blockIdx.z;
  const float* A = (z == 0) ? q : (z == 1) ? k : v;
  const unsigned short* W = (z == 0) ? wqb : (z == 1) ? wkb : wvb;

  const int tid = threadIdx.x;
  const int wave = tid >> 6, lane = tid & 63;
  const int wr = wave >> 1, wc = wave & 1;
  const int bm0 = blockIdx.x * 128;
  const int bn0 = blockIdx.y * 128;
  const int l15 = lane & 15, l4 = lane >> 4;

  f32x4 acc[4][4];
#pragma unroll
  for (int m = 0; m < 4; m++)
#pragma unroll
    for (int n = 0; n < 4; n++) { f32x4 zz = {0.f, 0.f, 0.f, 0.f}; acc[m][n] = zz; }

  for (int k0 = 0; k0 < K_; k0 += 64) {
#pragma unroll
    for (int it = 0; it < 4; ++it) {
      const int base = it * 256 + wave * 64;
      const int ch = base + lane;
      const int r = ch >> 3, c = ch & 7;
      gld16(W + (size_t)(bn0 + r) * K_ + (k0 + c * 8), Bs + base * 8);
    }
#pragma unroll
    for (int it = 0; it < 4; ++it) {
      const int ch = it * 256 + tid;
      const int r = ch >> 3, c = ch & 7;
      const float* g = A + (size_t)(bm0 + r) * K_ + (k0 + c * 8);
      float4v x0 = *(const float4v*)g;
      float4v x1 = *(const float4v*)(g + 4);
      u16x8 pp;
      pp[0]=f2bf(x0[0]); pp[1]=f2bf(x0[1]); pp[2]=f2bf(x0[2]); pp[3]=f2bf(x0[3]);
      pp[4]=f2bf(x1[0]); pp[5]=f2bf(x1[1]); pp[6]=f2bf(x1[2]); pp[7]=f2bf(x1[3]);
      *(u16x8*)&As[ch * 8] = pp;
    }
    __syncthreads();
#pragma unroll
    for (int ks = 0; ks < 2; ++ks) {
      const int kc = ks * 32 + l4 * 8;
      bf16x8 af[4], bfr[4];
#pragma unroll
      for (int m = 0; m < 4; m++) af[m] = *(const bf16x8*)&As[(wr * 64 + m * 16 + l15) * 64 + kc];
#pragma unroll
      for (int n = 0; n < 4; n++) bfr[n] = *(const bf16x8*)&Bs[(wc * 64 + n * 16 + l15) * 64 + kc];
#pragma unroll
      for (int m = 0; m < 4; m++)
#pragma unroll
        for (int n = 0; n < 4; n++)
          acc[m][n] = __builtin_amdgcn_mfma_f32_16x16x32_bf16(af[m], bfr[n], acc[m][n], 0, 0, 0);
    }
    __syncthreads();
  }

  if (z < 2) {
    unsigned short* O = (z == 0) ? Qh : Kh;
    const float qsc = (z == 0) ? SCALEQ_ : 1.f;
#pragma unroll
    for (int m = 0; m < 4; m++) {
      const int rr = bm0 + wr * 64 + m * 16 + l4 * 4;
#pragma unroll
      for (int n = 0; n < 4; n++) {
        const int cc = bn0 + wc * 64 + n * 16 + l15;
        const int h = cc >> 7, dh = cc & 127;
#pragma unroll
        for (int j = 0; j < 4; j++) {
          const int r2 = rr + j;
          O[((size_t)((r2 >> 11) * H_ + h) * L_ + (r2 & 2047)) * DH_ + dh] = f2bf(acc[m][n][j] * qsc);
        }
      }
    }
  } else {
    __syncthreads();
    unsigned short* T = smem;  // [128][136]
#pragma unroll
    for (int m = 0; m < 4; m++)
#pragma unroll
      for (int n = 0; n < 4; n++) {
        const int cl = wc * 64 + n * 16 + l15;
        const int rl = wr * 64 + m * 16 + l4 * 4;
#pragma unroll
        for (int j = 0; j < 4; j++) T[cl * 136 + rl + j] = f2bf(acc[m][n][j]);
      }
    __syncthreads();
    const int b = bm0 >> 11, lbase = bm0 & 2047;
    const int hb = bn0 >> 7;
#pragma unroll
    for (int it = 0; it < 8; ++it) {
      const int idx = it * 256 + tid;
      const int dhl = idx >> 4, c = idx & 15;
      u16x8 val = *(const u16x8*)&T[dhl * 136 + c * 8];
      *(u16x8*)&Vt[((size_t)(b * H_ + hb) * DH_ + dhl) * L_ + lbase + c * 8] = val;
    }
  }
}

// ---------------- causal flash attention: QBLK=128, KVBLK=128 (R8 structure) ----------------
// Swapped QK (lane holds q-row l15), in-reg softmax. K dbuf, V prefetch-at-top.
// R10 changes vs R8: Ps stride 144 -> 136 shorts (272 B == 16 mod 128 -> 2-way = free,
// 16B-aligned b128 reads); T13 defer-max (skip alpha/rescale when __all(mx <= m_r + 8)).
__global__ __launch_bounds__(512, 2) void attn_kernel(
    const unsigned short* __restrict__ Qh, const unsigned short* __restrict__ Kh,
    const unsigned short* __restrict__ Vt, unsigned short* __restrict__ ctx) {
  __shared__ unsigned short Ks[2][128 * 128];  // 64 KB
  __shared__ unsigned short Vs[128 * 128];     // 32 KB
  __shared__ unsigned short Ps[8][16 * 136];   // 34 KB, per-wave P [qrow16][key128+pad]

  const int lin0 = blockIdx.x + 8 * blockIdx.y;
  const int w = (lin0 & 7) * 32 + (lin0 >> 3);  // 8 same-bh blocks per XCD (KV L2 locality)
  const int pair = w & 7, bh = w >> 3;

  const size_t hoff = (size_t)bh * L_ * DH_;
  const unsigned short* Qp = Qh + hoff;
  const unsigned short* Kp = Kh + hoff;
  const unsigned short* Vp = Vt + hoff;

  const int tid = threadIdx.x, wave = tid >> 6, lane = tid & 63;
  const int l15 = lane & 15, l4 = lane >> 4;
  const int b = bh >> 4, h = bh & 15;

#define STAGEK(kt, buf) do { \
  _Pragma("unroll") \
  for (int it = 0; it < 4; ++it) { \
    const int ch = it * 512 + tid; \
    const int r = ch >> 4, s2 = ch & 15; \
    gld16(Kp + (size_t)((kt) * 128 + r) * DH_ + ((s2 ^ (r & 7)) * 8), (unsigned short*)&Ks[buf][0] + ch * 8); \
  } } while (0)
#define STAGEV(kt) do { \
  _Pragma("unroll") \
  for (int it = 0; it < 4; ++it) { \
    const int ch = it * 512 + tid; \
    const int r = ch >> 4, s2 = ch & 15; \
    gld16(Vp + (size_t)r * L_ + (kt) * 128 + ((s2 ^ (r & 7)) * 8), (unsigned short*)Vs + ch * 8); \
  } } while (0)

#pragma unroll 1
  for (int pp = 0; pp < 2; ++pp) {
    const int qt = pp ? (15 - pair) : pair;
    const int nt = qt + 1;

    bf16x8 qf[4];
    {
      const int qrow = qt * 128 + wave * 16 + l15;
#pragma unroll
      for (int s = 0; s < 4; s++)
        qf[s] = *(const bf16x8*)&Qp[(size_t)qrow * DH_ + s * 32 + l4 * 8];
    }

    f32x4 o[8];
#pragma unroll
    for (int df = 0; df < 8; df++) { f32x4 zz = {0.f, 0.f, 0.f, 0.f}; o[df] = zz; }
    float m_r = -1e30f;
    float l_r = 0.f;

    int p = 0;
    STAGEK(0, 0);
    VMCNT(0);
    BAR();

    const int qg = qt * 128 + wave * 16 + l15;
#pragma unroll 1
    for (int kt = 0; kt < nt; ++kt) {
      if (kt + 1 < nt) STAGEK(kt + 1, p ^ 1);
      STAGEV(kt);

      // S^T: sa[f][j] = S[qrow=l15][key = kt*128 + f*16 + l4*4 + j]
      f32x4 sa[8];
#pragma unroll
      for (int f = 0; f < 8; f++) { f32x4 zz = {0.f, 0.f, 0.f, 0.f}; sa[f] = zz; }
      __builtin_amdgcn_s_setprio(1);
#pragma unroll
      for (int ks = 0; ks < 4; ++ks) {
        const int c = ks * 4 + l4;
#pragma unroll
        for (int f = 0; f < 8; ++f) {
          const int n = f * 16 + l15;
          bf16x8 kf = *(const bf16x8*)&Ks[p][n * 128 + ((c ^ (n & 7)) * 8)];
          sa[f] = __builtin_amdgcn_mfma_f32_16x16x32_bf16(kf, qf[ks], sa[f], 0, 0, 0);
        }
      }
      __builtin_amdgcn_s_setprio(0);

      if (kt == qt) {
#pragma unroll
        for (int f = 0; f < 8; f++) {
          const int kg = kt * 128 + f * 16 + l4 * 4;
#pragma unroll
          for (int j = 0; j < 4; j++)
            if (kg + j > qg) sa[f][j] = -1e30f;
        }
      }

      // in-reg row softmax (row l15, replicated across 4 l4-lanes)
      float mx = -1e30f;
#pragma unroll
      for (int f = 0; f < 8; f++)
#pragma unroll
        for (int j = 0; j < 4; j++) mx = fmaxf(mx, sa[f][j]);
      mx = fmaxf(mx, __shfl_xor(mx, 16));
      mx = fmaxf(mx, __shfl_xor(mx, 32));

      // T13 defer-max: only rescale when the new tile's max exceeds m_r + 8
      if (!__all(mx <= m_r + 8.f)) {
        const float mnew = fmaxf(m_r, mx);
        const float alpha = exp2i(m_r - mnew);
        l_r *= alpha;
        m_r = mnew;
#pragma unroll
        for (int j = 0; j < 4; j++) {
          const float aj = __shfl(alpha, l4 * 4 + j);
#pragma unroll
          for (int df = 0; df < 8; df++) o[df][j] *= aj;
        }
      }

      float rs = 0.f;
#pragma unroll
      for (int f = 0; f < 8; f++) {
        u16x4 pk4;
#pragma unroll
        for (int j = 0; j < 4; j++) {
          float pv = exp2i(sa[f][j] - m_r);
          rs += pv;
          pk4[j] = f2bf(pv);
        }
        *(u16x4*)&Ps[wave][l15 * 136 + f * 16 + l4 * 4] = pk4;
      }
      rs += __shfl_xor(rs, 16);
      rs += __shfl_xor(rs, 32);
      l_r += rs;

      VMCNT(0);   // drains K(t+1) + V(t) stages (in flight under QK+softmax)
      BAR();      // V writes visible to all waves

      __builtin_amdgcn_s_setprio(1);
#pragma unroll
      for (int ksl = 0; ksl < 4; ++ksl) {
        const int pc = ksl * 4 + l4;
        bf16x8 pf = *(const bf16x8*)&Ps[wave][l15 * 136 + ksl * 32 + l4 * 8];
#pragma unroll
        for (int df = 0; df < 8; ++df) {
          const int vr = df * 16 + l15;
          bf16x8 vf = *(const bf16x8*)&Vs[vr * 128 + ((pc ^ (vr & 7)) * 8)];
          o[df] = __builtin_amdgcn_mfma_f32_16x16x32_bf16(pf, vf, o[df], 0, 0, 0);
        }
      }
      __builtin_amdgcn_s_setprio(0);
      BAR();      // V reads retired before next tile's STAGEV overwrite
      p ^= 1;
    }

#pragma unroll
    for (int j = 0; j < 4; j++) {
      const float inv = 1.0f / __shfl(l_r, l4 * 4 + j);
      const int lq = qt * 128 + wave * 16 + l4 * 4 + j;
      const size_t rowb = ((size_t)(b * L_ + lq)) * D_ + h * DH_;
#pragma unroll
      for (int df = 0; df < 8; ++df)
        ctx[rowb + df * 16 + l15] = f2bf(o[df][j] * inv);
    }
  }
#undef STAGEK
#undef STAGEV
}

extern "C" void kernel_launch(void* const* d_in, const int* in_sizes, int n_in,
                              void* d_out, int out_size, void* d_ws, size_t ws_size,
                              hipStream_t stream) {
  const float* q  = (const float*)d_in[0];
  const float* k  = (const float*)d_in[1];
  const float* v  = (const float*)d_in[2];
  // d_in[3] = attn_mask: fixed causal triu(k=1); implemented analytically in-kernel
  const float* wq = (const float*)d_in[4];
  const float* wk = (const float*)d_in[5];
  const float* wv = (const float*)d_in[6];
  const float* wo = (const float*)d_in[7];

  const size_t DD = (size_t)D_ * D_;
  const size_t BLD = (size_t)B_ * L_ * D_;
  unsigned short* ws  = (unsigned short*)d_ws;
  unsigned short* wqb = ws;
  unsigned short* wkb = wqb + DD;
  unsigned short* wvb = wkb + DD;
  unsigned short* wob = wvb + DD;

  const size_t need_full = (4 * DD + 7 * BLD) * 2;  // ~151 MB

  if (ws_size >= need_full) {
    unsigned short* qb  = wob + DD;
    unsigned short* kb  = qb + BLD;
    unsigned short* vb  = kb + BLD;
    unsigned short* QhP = vb + BLD;
    unsigned short* KhP = QhP + BLD;
    unsigned short* VtP = KhP + BLD;
    unsigned short* ctx = VtP + BLD;

    cvt_all<<<dim3(4096, 1, 7), 256, 0, stream>>>(wq, wk, wv, wo, q, k, v, ws, 3);
    gemm256<<<dim3(16, 8, 2), 512, 0, stream>>>(kb, vb, wkb, wvb, KhP, VtP);
    gemm8p<1><<<dim3(32, 8), 512, 0, stream>>>(qb, wqb, QhP);
    attn_kernel<<<dim3(8, 32), 512, 0, stream>>>(QhP, KhP, VtP, ctx);
    gemm8p<0><<<dim3(32, 8), 512, 0, stream>>>(ctx, wob, d_out);
  } else {
    unsigned short* QhP = wob + DD;
    unsigned short* KhP = QhP + BLD;
    unsigned short* VtP = KhP + BLD;
    unsigned short* ctx = VtP + BLD;

    cvt_all<<<dim3(4096, 1, 4), 256, 0, stream>>>(wq, wk, wv, wo, q, k, v, ws, 0);
    proj_gemm_f32a<<<dim3(32, 16, 3), 256, 0, stream>>>(q, k, v, wqb, wkb, wvb, QhP, KhP, VtP);
    attn_kernel<<<dim3(8, 32), 512, 0, stream>>>(QhP, KhP, VtP, ctx);
    gemm8p<0><<<dim3(32, 8), 512, 0, stream>>>(ctx, wob, d_out);
  }
}